// Round 18
// baseline (566.192 us; speedup 1.0000x reference)
//
#include <hip/hip_runtime.h>
#include <hip/hip_bf16.h>
#include <math.h>

#define N_SP 65536   // h*w
#define IMG  256

typedef __attribute__((ext_vector_type(8))) short s16x8;
typedef __attribute__((ext_vector_type(4))) float f32x4;

// Packed fp32->bf16 hi/lo split (round-18): __float22bfloat162_rn maps to
// v_cvt_pk_bf16_f32 (RNE, 2 elems/instr) -- ~3 VALU/elem vs ~8 for the old
// bit-math version (guide m240: don't hand-write bf16 conversion).
// Low u16 of H = bf16(a), high = bf16(b)  (same order as the old pk2(h0,h1)).
__device__ __forceinline__ void split2(float a, float b, uint &H, uint &L) {
    union { __hip_bfloat162 h2; uint u; } hc, lc;
    hc.h2 = __float22bfloat162_rn(float2{a, b});
    const float ra = a - __uint_as_float(hc.u << 16);
    const float rb = b - __uint_as_float(hc.u & 0xFFFF0000u);
    lc.h2 = __float22bfloat162_rn(float2{ra, rb});
    H = hc.u; L = lc.u;
}
union u4s8 { uint4 u; s16x8 v; };

// Direct HBM->LDS DMA, 16B per lane. LDS dest = wave-uniform base + lane*16.
__device__ __forceinline__ void load_lds16f(const float* g, float* l) {
    __builtin_amdgcn_global_load_lds(
        (const __attribute__((address_space(1))) void*)g,
        (__attribute__((address_space(3))) void*)l, 16, 0, 0);
}

// ---------------------------------------------------------------------------
// gemm_xf: C[m][n] = sum_k Wf[wrow0+m][k] * X[k][n], K=192, split-bf16
// (C = Whi*Xhi + Whi*Xlo + Wlo*Xhi; lo*lo dropped, ~1e-5 rel).
// X read directly in fp32 [k][N_SP] (round-17; no plane intermediate):
// staged as fp32 32x256 tile via global_load_lds, B-fragments gathered from
// the LDS column and split to hi/lo in regs (round-18: packed cvt).
// W converted in-kernel. Round-14 dbuf / round-10 reg-prefetch regressed --
// do not revisit. T1 swizzle (round-16): flat grid nm*256; d: r=d&7, q=d>>3,
// m=(q%nm), n=(q/nm)*8+r -> same-n m-blocks share an XCD, adjacent in time.
// C/D (m89): col=lane&15, row=(lane>>4)*4+j.
// ---------------------------------------------------------------------------
__global__ __launch_bounds__(256) void gemm_xf(
    const float* __restrict__ Wf, int wrow0, int nm,
    const float* __restrict__ X, float* __restrict__ C)
{
    __shared__ ushort WsH[64][40], WsL[64][40];
    __shared__ float Xs[32 * 256];          // [k][n] linear, 1KB rows
    const int t  = threadIdx.x;
    const int wv = t >> 6, l = t & 63;
    const int lc = l & 15, lg = l >> 4;
    const int d = blockIdx.x;
    const int r = d & 7, q = d >> 3;
    const int m0 = (q % nm) * 64;
    const long long n0 = (long long)((q / nm) * 8 + r) * 256;

    f32x4 acc[4][4];
    #pragma unroll
    for (int i = 0; i < 4; ++i)
        #pragma unroll
        for (int j = 0; j < 4; ++j) acc[i][j] = (f32x4)(0.f);

    const int ar = t >> 2, ak = (t & 3) * 8;
    const int rXk = wv * 8;                 // wave stages X rows [wv*8, wv*8+8)

    for (int kc = 0; kc < 192; kc += 32) {
        // 1) X tile DMA: 8 rows/wave, 1KB each (lane l -> +l*16B)
        #pragma unroll
        for (int i = 0; i < 8; ++i) {
            load_lds16f(X + (long long)(kc + rXk + i) * N_SP + n0 + l * 4,
                        &Xs[(rXk + i) * 256]);
        }
        // 2) W tile: fp32 load, packed hi/lo split, ds_write (overlaps DMA)
        {
            const float* wp = Wf + (long long)(wrow0 + m0 + ar) * 192 + kc + ak;
            const float4 a0 = *(const float4*)wp;
            const float4 a1 = *(const float4*)(wp + 4);
            uint4 H, L;
            split2(a0.x, a0.y, H.x, L.x);
            split2(a0.z, a0.w, H.y, L.y);
            split2(a1.x, a1.y, H.z, L.z);
            split2(a1.z, a1.w, H.w, L.w);
            *(uint4*)&WsH[ar][ak] = H;
            *(uint4*)&WsL[ar][ak] = L;
        }
        __syncthreads();

        s16x8 ah[4], al[4];
        #pragma unroll
        for (int mf = 0; mf < 4; ++mf) {
            ah[mf] = *(const s16x8*)&WsH[mf * 16 + lc][lg * 8];
            al[mf] = *(const s16x8*)&WsL[mf * 16 + lc][lg * 8];
        }
        #pragma unroll
        for (int nf = 0; nf < 4; ++nf) {
            const int nr = wv * 64 + nf * 16 + lc;
            const int cb = (lg * 8) * 256 + nr;
            u4s8 BH, BL;
            split2(Xs[cb],          Xs[cb + 256],  BH.u.x, BL.u.x);
            split2(Xs[cb + 512],    Xs[cb + 768],  BH.u.y, BL.u.y);
            split2(Xs[cb + 1024],   Xs[cb + 1280], BH.u.z, BL.u.z);
            split2(Xs[cb + 1536],   Xs[cb + 1792], BH.u.w, BL.u.w);
            #pragma unroll
            for (int mf = 0; mf < 4; ++mf) {
                acc[mf][nf] = __builtin_amdgcn_mfma_f32_16x16x32_bf16(ah[mf], BH.v, acc[mf][nf], 0, 0, 0);
                acc[mf][nf] = __builtin_amdgcn_mfma_f32_16x16x32_bf16(ah[mf], BL.v, acc[mf][nf], 0, 0, 0);
                acc[mf][nf] = __builtin_amdgcn_mfma_f32_16x16x32_bf16(al[mf], BH.v, acc[mf][nf], 0, 0, 0);
            }
        }
        __syncthreads();
    }

    #pragma unroll
    for (int mf = 0; mf < 4; ++mf)
        #pragma unroll
        for (int nf = 0; nf < 4; ++nf) {
            const long long nn = n0 + wv * 64 + nf * 16 + lc;
            #pragma unroll
            for (int j = 0; j < 4; ++j)
                C[(long long)(m0 + mf * 16 + lg * 4 + j) * N_SP + nn] = acc[mf][nf][j];
        }
}

// ---------------------------------------------------------------------------
// dwconv8: depthwise 3x3, register-shift, 8 px x 4 channels per thread.
// fp32 [c][n] in/out. Halo via clamped loads + zeroed weights.
// ---------------------------------------------------------------------------
__global__ __launch_bounds__(256) void dwconv8(
    const float* __restrict__ src, const float* __restrict__ dww, float* __restrict__ dst)
{
    const int t = threadIdx.x;
    const int s = blockIdx.x * 256 + t;
    const int y = s >> 5;
    const int x8 = (s & 31) * 8;
    const int cg = blockIdx.y;

    const int xl = (x8 == 0) ? 0 : x8 - 4;
    const int xr = (x8 == 248) ? 248 : x8 + 8;

    #pragma unroll
    for (int i = 0; i < 4; ++i) {
        const int c = cg * 4 + i;
        const float* base = src + ((long long)c << 16);
        const float* wp = dww + c * 9;
        float acc[8];
        #pragma unroll
        for (int j = 0; j < 8; ++j) acc[j] = 0.f;
        #pragma unroll
        for (int dy = 0; dy < 3; ++dy) {
            const int yy = y + dy - 1;
            const bool vld = (yy >= 0 && yy < IMG);
            const float* row = base + (vld ? yy : y) * IMG;
            const float w0 = vld ? wp[dy * 3 + 0] : 0.f;
            const float w1 = vld ? wp[dy * 3 + 1] : 0.f;
            const float w2 = vld ? wp[dy * 3 + 2] : 0.f;
            const float4 Lq = *(const float4*)(row + xl);
            const float4 M0 = *(const float4*)(row + x8);
            const float4 M1 = *(const float4*)(row + x8 + 4);
            const float4 Rq = *(const float4*)(row + xr);
            float vv[10];
            vv[0] = (x8 == 0) ? 0.f : Lq.w;
            vv[1] = M0.x; vv[2] = M0.y; vv[3] = M0.z; vv[4] = M0.w;
            vv[5] = M1.x; vv[6] = M1.y; vv[7] = M1.z; vv[8] = M1.w;
            vv[9] = (x8 == 248) ? 0.f : Rq.x;
            #pragma unroll
            for (int j = 0; j < 8; ++j)
                acc[j] = fmaf(w0, vv[j], fmaf(w1, vv[j + 1], fmaf(w2, vv[j + 2], acc[j])));
        }
        float4 o0, o1;
        o0.x = acc[0]; o0.y = acc[1]; o0.z = acc[2]; o0.w = acc[3];
        o1.x = acc[4]; o1.y = acc[5]; o1.z = acc[6]; o1.w = acc[7];
        float* drow = dst + ((long long)c << 16) + y * IMG + x8;
        *(float4*)drow = o0;
        *(float4*)(drow + 4) = o1;
    }
}

// ---------------------------------------------------------------------------
// gred: G/Sq/Sk partials from post-DW q,k. q,k tiles staged in LDS once
// (coalesced, unique); compute reads LDS (8-lane sharing = broadcast).
// Reduction scratch overlays staging LDS. No atomics.
// ---------------------------------------------------------------------------
__global__ __launch_bounds__(256) void gred(
    const float* __restrict__ q, const float* __restrict__ k, float* __restrict__ Gpart)
{
    __shared__ float smem[8448];          // qs: [0,4224) ks: [4224,8448); stride 132
    float* qs = smem;
    float* ks = smem + 4224;
    const int t = threadIdx.x;
    const int blk = blockIdx.x, h = blockIdx.y;
    const int w = t >> 6, l = t & 63;
    const int cqd = l >> 3, dqd = l & 7;

    float acc[4][4];
    #pragma unroll
    for (int i = 0; i < 4; ++i) { acc[i][0]=0.f; acc[i][1]=0.f; acc[i][2]=0.f; acc[i][3]=0.f; }
    float sq[4] = {0.f,0.f,0.f,0.f}, sk[4] = {0.f,0.f,0.f,0.f};

    const float* qh = q + ((long long)(h * 32) << 16);
    const float* kh = k + ((long long)(h * 32) << 16);

    for (int s = 0; s < 4; ++s) {
        const int n0s = blk * 512 + s * 128;
        #pragma unroll
        for (int i = 0; i < 4; ++i) {
            const int f4 = t + i * 256;
            const int ch = f4 >> 5, n4 = (f4 & 31) * 4;
            const long long go = ((long long)ch << 16) + n0s + n4;
            *(float4*)&qs[ch * 132 + n4] = *(const float4*)(qh + go);
            *(float4*)&ks[ch * 132 + n4] = *(const float4*)(kh + go);
        }
        __syncthreads();
        const int nb = w * 32;
        #pragma unroll
        for (int it = 0; it < 8; ++it) {
            const int n = nb + it * 4;
            float4 qa[4], kb[4];
            #pragma unroll
            for (int i = 0; i < 4; ++i) qa[i] = *(const float4*)&qs[(cqd * 4 + i) * 132 + n];
            #pragma unroll
            for (int j = 0; j < 4; ++j) kb[j] = *(const float4*)&ks[(dqd * 4 + j) * 132 + n];
            #pragma unroll
            for (int i = 0; i < 4; ++i) {
                #pragma unroll
                for (int j = 0; j < 4; ++j) {
                    acc[i][j] = fmaf(qa[i].x, kb[j].x, acc[i][j]);
                    acc[i][j] = fmaf(qa[i].y, kb[j].y, acc[i][j]);
                    acc[i][j] = fmaf(qa[i].z, kb[j].z, acc[i][j]);
                    acc[i][j] = fmaf(qa[i].w, kb[j].w, acc[i][j]);
                }
            }
            if (dqd == 0) {
                #pragma unroll
                for (int i = 0; i < 4; ++i) {
                    sq[i] = fmaf(qa[i].x, qa[i].x, sq[i]);
                    sq[i] = fmaf(qa[i].y, qa[i].y, sq[i]);
                    sq[i] = fmaf(qa[i].z, qa[i].z, sq[i]);
                    sq[i] = fmaf(qa[i].w, qa[i].w, sq[i]);
                }
            }
            if (cqd == 0) {
                #pragma unroll
                for (int j = 0; j < 4; ++j) {
                    sk[j] = fmaf(kb[j].x, kb[j].x, sk[j]);
                    sk[j] = fmaf(kb[j].y, kb[j].y, sk[j]);
                    sk[j] = fmaf(kb[j].z, kb[j].z, sk[j]);
                    sk[j] = fmaf(kb[j].w, kb[j].w, sk[j]);
                }
            }
        }
        __syncthreads();
    }

    float* red  = smem;                   // overlays (staging dead post-barrier)
    float* red2 = smem + 4096;
    #pragma unroll
    for (int i = 0; i < 4; ++i) {
        #pragma unroll
        for (int j = 0; j < 4; ++j)
            red[w * 1024 + (cqd * 4 + i) * 32 + dqd * 4 + j] = acc[i][j];
    }
    if (dqd == 0) {
        #pragma unroll
        for (int i = 0; i < 4; ++i) red2[w * 32 + cqd * 4 + i] = sq[i];
    }
    if (cqd == 0) {
        #pragma unroll
        for (int j = 0; j < 4; ++j) red2[128 + w * 32 + dqd * 4 + j] = sk[j];
    }
    __syncthreads();

    float* Gp = Gpart + (long long)(h * 128 + blk) * 1088;
    #pragma unroll
    for (int i = 0; i < 4; ++i) {
        int slot = t + i * 256;
        Gp[slot] = red[slot] + red[1024 + slot] + red[2048 + slot] + red[3072 + slot];
    }
    if (t < 32) {
        Gp[1024 + t] = red2[t] + red2[32 + t] + red2[64 + t] + red2[96 + t];
    } else if (t < 64) {
        int c = t - 32;
        Gp[1056 + c] = red2[128 + c] + red2[160 + c] + red2[192 + c] + red2[224 + c];
    }
}

__global__ void reduce_g(const float* __restrict__ Gpart, float* __restrict__ G,
                         float* __restrict__ Sq, float* __restrict__ Sk, int bh0)
{
    const int h = blockIdx.x, t = threadIdx.x;
    const float* Gp = Gpart + (long long)h * 128 * 1088;
    const int bh = bh0 + h;
    #pragma unroll
    for (int i = 0; i < 5; ++i) {
        int slot = t + i * 256;
        if (slot >= 1088) break;
        float s = 0.f;
        for (int tl = 0; tl < 128; ++tl) s += Gp[(long long)tl * 1088 + slot];
        if (slot < 1024)      G[(long long)bh * 1024 + slot] = s;
        else if (slot < 1056) Sq[bh * 32 + (slot - 1024)] = s;
        else                  Sk[bh * 32 + (slot - 1056)] = s;
    }
}

__global__ void attn_small(const float* __restrict__ G, const float* __restrict__ Sq,
                           const float* __restrict__ Sk, const float* __restrict__ temp,
                           const float* __restrict__ attn1, float* __restrict__ A)
{
    const int h = blockIdx.x, b = blockIdx.y, c = threadIdx.x;
    const int bh = b * 6 + h;
    const float* g = G + ((long long)bh * 32 + c) * 32;
    const float nq = fmaxf(sqrtf(Sq[bh * 32 + c]), 1e-12f);
    const float T  = temp[h];
    const float a1 = attn1[0];

    float a[32];
    #pragma unroll
    for (int d = 0; d < 32; ++d) {
        float nk = fmaxf(sqrtf(Sk[bh * 32 + d]), 1e-12f);
        a[d] = g[d] / (nq * nk) * T;
    }
    unsigned mask = 0u;
    float m = 0.f, kth = 0.f;
    for (int it = 0; it < 16; ++it) {
        float best = -3.4e38f; int bi = 0;
        #pragma unroll
        for (int d = 0; d < 32; ++d) {
            bool avail = ((mask >> d) & 1u) == 0u;
            if (avail && a[d] > best) { best = a[d]; bi = d; }
        }
        mask |= (1u << bi);
        if (it == 0) m = best;
        kth = best;
    }
    float denom = 0.f;
    #pragma unroll
    for (int d = 0; d < 32; ++d) if (a[d] >= kth) denom += expf(a[d] - m);
    const float inv = a1 / denom;
    float* Ar = A + ((long long)bh * 32 + c) * 32;
    #pragma unroll
    for (int d = 0; d < 32; ++d) Ar[d] = (a[d] >= kth) ? expf(a[d] - m) * inv : 0.f;
}

__global__ void make_m(const float* __restrict__ proj_w, const float* __restrict__ A,
                       float* __restrict__ M)
{
    const int o = blockIdx.x, b = blockIdx.y, j = threadIdx.x;
    const int hd = j >> 5, d = j & 31;
    const float* pw = proj_w + o * 192 + hd * 32;
    const float* Ah = A + ((long long)(b * 6 + hd) * 32) * 32 + d;
    float s = 0.f;
    #pragma unroll
    for (int cq = 0; cq < 32; ++cq) s = fmaf(pw[cq], Ah[cq * 32], s);
    M[((long long)(b * 192 + o)) * 192 + j] = s;
}

// ---------------------------------------------------------------------------
extern "C" void kernel_launch(void* const* d_in, const int* in_sizes, int n_in,
                              void* d_out, int out_size, void* d_ws, size_t ws_size,
                              hipStream_t stream)
{
    const float* x      = (const float*)d_in[0];
    const float* qkv_w  = (const float*)d_in[1];
    const float* dww    = (const float*)d_in[2];
    const float* proj_w = (const float*)d_in[3];
    const float* temp   = (const float*)d_in[4];
    const float* attn1  = (const float*)d_in[5];
    float* out = (float*)d_out;
    float* wsf = (float*)d_ws;

    // ws layout (floats) -- proven-safe 101,059,584 bytes total
    float* G   = wsf;                 // 12,288
    float* Sq  = G + 12288;           // 384
    float* Sk  = Sq + 384;            // 384
    float* A   = Sk + 384;            // 12,288
    float* Mm  = A + 12288;           // 73,728
    float* buf = Mm + 73728;          // 96 MiB (= 384 x 65536 floats exactly)

    const long long PL = 12582912LL;  // floats per 48 MiB region
    float* W1 = buf;                  // buf rows 0-191
    float* W2 = buf + PL;             // buf rows 192-383
    float* R1 = out;                  // batch-0 out region (scratch until final)
    float* R2 = out + PL;             // batch-1 out region

    // ---- Phase S (attention statistics) per batch: q,k never persist
    for (int b = 0; b < 2; ++b) {
        const float* xb = x + (long long)b * PL;
        gemm_xf<<<dim3(1536), 256, 0, stream>>>(qkv_w, 0, 6, xb, buf);   // q@W1,k@W2
        dwconv8<<<dim3(32, 48), 256, 0, stream>>>(W1, dww, R1);          // qpost
        dwconv8<<<dim3(32, 48), 256, 0, stream>>>(W2, dww + 192 * 9, R2);// kpost
        gred<<<dim3(128, 6), 256, 0, stream>>>(R1, R2, W1);              // Gpart@W1
        reduce_g<<<dim3(6, 1), 256, 0, stream>>>(W1, G, Sq, Sk, b * 6);
    }

    // ---- Phase B: tiny attention matrices + fused projection matrices
    attn_small<<<dim3(6, 2), 32, 0, stream>>>(G, Sq, Sk, temp, attn1, A);
    make_m<<<dim3(192, 2), 192, 0, stream>>>(proj_w, A, Mm);

    // ---- Phase V+K4 per batch: K1v -> W1 ; dw -> W2 ; out_b = M_b @ vpost
    for (int b = 0; b < 2; ++b) {
        const float* xb = x + (long long)b * PL;
        float* outb = out + (long long)b * PL;
        gemm_xf<<<dim3(768), 256, 0, stream>>>(qkv_w, 384, 3, xb, W1);
        dwconv8<<<dim3(32, 48), 256, 0, stream>>>(W1, dww + 384 * 9, W2);
        gemm_xf<<<dim3(768), 256, 0, stream>>>(Mm + (long long)b * 36864, 0, 3, W2, outb);
    }
}

// Round 19
// 534.237 us; speedup vs baseline: 1.0598x; 1.0598x over previous
//
#include <hip/hip_runtime.h>
#include <math.h>

#define N_SP 65536   // h*w
#define IMG  256

typedef __attribute__((ext_vector_type(8))) short s16x8;
typedef __attribute__((ext_vector_type(4))) float f32x4;

// RNE fp32->bf16 (bit version, deterministic) and back.
// Round-18 lesson: the "packed" __float22bfloat162_rn version raised VGPR
// 80->108 (occupancy 25->19%) and cost +25us total -- keep the bit-math.
__device__ inline ushort f2bf(float f) {
    uint u = __float_as_uint(f);
    return (ushort)((u + 0x7FFFu + ((u >> 16) & 1u)) >> 16);
}
__device__ inline float bf2f(ushort h) { return __uint_as_float(((uint)h) << 16); }
__device__ inline uint pk2(ushort a, ushort b) { return (uint)a | ((uint)b << 16); }

// Direct HBM->LDS DMA, 16B per lane. LDS dest = wave-uniform base + lane*16.
__device__ __forceinline__ void load_lds16f(const float* g, float* l) {
    __builtin_amdgcn_global_load_lds(
        (const __attribute__((address_space(1))) void*)g,
        (__attribute__((address_space(3))) void*)l, 16, 0, 0);
}

// ---------------------------------------------------------------------------
// gemm_xf: C[m][n] = sum_k Wf[wrow0+m][k] * X[k][n], K=192, split-bf16
// (C = Whi*Xhi + Whi*Xlo + Wlo*Xhi; lo*lo dropped, ~1e-5 rel).
// X read directly in fp32 [k][N_SP] (round-17; no plane intermediate):
// staged as fp32 32x256 tile via global_load_lds, B-fragments gathered from
// the LDS column and split to hi/lo in regs (bit-math f2bf).
// ROUND-19: Ws planes LINEAR [64][32] (pad dropped) -> LDS total 40,960 B =
// exactly 4 blocks/CU (was 43,008 -> 3). The 8-way W-read conflict this
// creates is the class round-9 proved time-invariant in this structure.
// Round-14 dbuf / round-10 reg-prefetch / round-18 packed-cvt all regressed
// -- do not revisit. T1 swizzle (round-16): flat grid nm*256; d: r=d&7,
// q=d>>3, m=(q%nm), n=(q/nm)*8+r.
// C/D (m89): col=lane&15, row=(lane>>4)*4+j.
// ---------------------------------------------------------------------------
__global__ __launch_bounds__(256) void gemm_xf(
    const float* __restrict__ Wf, int wrow0, int nm,
    const float* __restrict__ X, float* __restrict__ C)
{
    __shared__ ushort WsH[64 * 32], WsL[64 * 32];   // linear, row r at r*32
    __shared__ float Xs[32 * 256];                  // [k][n] linear, 1KB rows
    const int t  = threadIdx.x;
    const int wv = t >> 6, l = t & 63;
    const int lc = l & 15, lg = l >> 4;
    const int d = blockIdx.x;
    const int r = d & 7, q = d >> 3;
    const int m0 = (q % nm) * 64;
    const long long n0 = (long long)((q / nm) * 8 + r) * 256;

    f32x4 acc[4][4];
    #pragma unroll
    for (int i = 0; i < 4; ++i)
        #pragma unroll
        for (int j = 0; j < 4; ++j) acc[i][j] = (f32x4)(0.f);

    const int ar = t >> 2, ak = (t & 3) * 8;
    const int rXk = wv * 8;                 // wave stages X rows [wv*8, wv*8+8)

    for (int kc = 0; kc < 192; kc += 32) {
        // 1) X tile DMA: 8 rows/wave, 1KB each (lane l -> +l*16B)
        #pragma unroll
        for (int i = 0; i < 8; ++i) {
            load_lds16f(X + (long long)(kc + rXk + i) * N_SP + n0 + l * 4,
                        &Xs[(rXk + i) * 256]);
        }
        // 2) W tile: fp32 load, hi/lo split, ds_write (overlaps DMA)
        {
            const float* wp = Wf + (long long)(wrow0 + m0 + ar) * 192 + kc + ak;
            const float4 a0 = *(const float4*)wp;
            const float4 a1 = *(const float4*)(wp + 4);
            const float v[8] = {a0.x, a0.y, a0.z, a0.w, a1.x, a1.y, a1.z, a1.w};
            ushort h[8], lo_[8];
            #pragma unroll
            for (int j = 0; j < 8; ++j) { h[j] = f2bf(v[j]); lo_[j] = f2bf(v[j] - bf2f(h[j])); }
            uint4 H, L;
            H.x = pk2(h[0],h[1]); H.y = pk2(h[2],h[3]); H.z = pk2(h[4],h[5]); H.w = pk2(h[6],h[7]);
            L.x = pk2(lo_[0],lo_[1]); L.y = pk2(lo_[2],lo_[3]); L.z = pk2(lo_[4],lo_[5]); L.w = pk2(lo_[6],lo_[7]);
            *(uint4*)&WsH[ar * 32 + ak] = H;
            *(uint4*)&WsL[ar * 32 + ak] = L;
        }
        __syncthreads();

        s16x8 ah[4], al[4];
        #pragma unroll
        for (int mf = 0; mf < 4; ++mf) {
            ah[mf] = *(const s16x8*)&WsH[(mf * 16 + lc) * 32 + lg * 8];
            al[mf] = *(const s16x8*)&WsL[(mf * 16 + lc) * 32 + lg * 8];
        }
        #pragma unroll
        for (int nf = 0; nf < 4; ++nf) {
            const int nr = wv * 64 + nf * 16 + lc;
            s16x8 bh, bl;
            #pragma unroll
            for (int s = 0; s < 8; ++s) {
                const float xv = Xs[(lg * 8 + s) * 256 + nr];
                const ushort hh = f2bf(xv);
                bh[s] = (short)hh;
                bl[s] = (short)f2bf(xv - bf2f(hh));
            }
            #pragma unroll
            for (int mf = 0; mf < 4; ++mf) {
                acc[mf][nf] = __builtin_amdgcn_mfma_f32_16x16x32_bf16(ah[mf], bh, acc[mf][nf], 0, 0, 0);
                acc[mf][nf] = __builtin_amdgcn_mfma_f32_16x16x32_bf16(ah[mf], bl, acc[mf][nf], 0, 0, 0);
                acc[mf][nf] = __builtin_amdgcn_mfma_f32_16x16x32_bf16(al[mf], bh, acc[mf][nf], 0, 0, 0);
            }
        }
        __syncthreads();
    }

    #pragma unroll
    for (int mf = 0; mf < 4; ++mf)
        #pragma unroll
        for (int nf = 0; nf < 4; ++nf) {
            const long long nn = n0 + wv * 64 + nf * 16 + lc;
            #pragma unroll
            for (int j = 0; j < 4; ++j)
                C[(long long)(m0 + mf * 16 + lg * 4 + j) * N_SP + nn] = acc[mf][nf][j];
        }
}

// ---------------------------------------------------------------------------
// dwconv8: depthwise 3x3, register-shift, 8 px x 4 channels per thread.
// fp32 [c][n] in/out. Halo via clamped loads + zeroed weights.
// ---------------------------------------------------------------------------
__global__ __launch_bounds__(256) void dwconv8(
    const float* __restrict__ src, const float* __restrict__ dww, float* __restrict__ dst)
{
    const int t = threadIdx.x;
    const int s = blockIdx.x * 256 + t;
    const int y = s >> 5;
    const int x8 = (s & 31) * 8;
    const int cg = blockIdx.y;

    const int xl = (x8 == 0) ? 0 : x8 - 4;
    const int xr = (x8 == 248) ? 248 : x8 + 8;

    #pragma unroll
    for (int i = 0; i < 4; ++i) {
        const int c = cg * 4 + i;
        const float* base = src + ((long long)c << 16);
        const float* wp = dww + c * 9;
        float acc[8];
        #pragma unroll
        for (int j = 0; j < 8; ++j) acc[j] = 0.f;
        #pragma unroll
        for (int dy = 0; dy < 3; ++dy) {
            const int yy = y + dy - 1;
            const bool vld = (yy >= 0 && yy < IMG);
            const float* row = base + (vld ? yy : y) * IMG;
            const float w0 = vld ? wp[dy * 3 + 0] : 0.f;
            const float w1 = vld ? wp[dy * 3 + 1] : 0.f;
            const float w2 = vld ? wp[dy * 3 + 2] : 0.f;
            const float4 Lq = *(const float4*)(row + xl);
            const float4 M0 = *(const float4*)(row + x8);
            const float4 M1 = *(const float4*)(row + x8 + 4);
            const float4 Rq = *(const float4*)(row + xr);
            float vv[10];
            vv[0] = (x8 == 0) ? 0.f : Lq.w;
            vv[1] = M0.x; vv[2] = M0.y; vv[3] = M0.z; vv[4] = M0.w;
            vv[5] = M1.x; vv[6] = M1.y; vv[7] = M1.z; vv[8] = M1.w;
            vv[9] = (x8 == 248) ? 0.f : Rq.x;
            #pragma unroll
            for (int j = 0; j < 8; ++j)
                acc[j] = fmaf(w0, vv[j], fmaf(w1, vv[j + 1], fmaf(w2, vv[j + 2], acc[j])));
        }
        float4 o0, o1;
        o0.x = acc[0]; o0.y = acc[1]; o0.z = acc[2]; o0.w = acc[3];
        o1.x = acc[4]; o1.y = acc[5]; o1.z = acc[6]; o1.w = acc[7];
        float* drow = dst + ((long long)c << 16) + y * IMG + x8;
        *(float4*)drow = o0;
        *(float4*)(drow + 4) = o1;
    }
}

// ---------------------------------------------------------------------------
// gred: G/Sq/Sk partials from post-DW q,k. q,k tiles staged in LDS once
// (coalesced, unique); compute reads LDS (8-lane sharing = broadcast).
// Reduction scratch overlays staging LDS. No atomics.
// ---------------------------------------------------------------------------
__global__ __launch_bounds__(256) void gred(
    const float* __restrict__ q, const float* __restrict__ k, float* __restrict__ Gpart)
{
    __shared__ float smem[8448];          // qs: [0,4224) ks: [4224,8448); stride 132
    float* qs = smem;
    float* ks = smem + 4224;
    const int t = threadIdx.x;
    const int blk = blockIdx.x, h = blockIdx.y;
    const int w = t >> 6, l = t & 63;
    const int cqd = l >> 3, dqd = l & 7;

    float acc[4][4];
    #pragma unroll
    for (int i = 0; i < 4; ++i) { acc[i][0]=0.f; acc[i][1]=0.f; acc[i][2]=0.f; acc[i][3]=0.f; }
    float sq[4] = {0.f,0.f,0.f,0.f}, sk[4] = {0.f,0.f,0.f,0.f};

    const float* qh = q + ((long long)(h * 32) << 16);
    const float* kh = k + ((long long)(h * 32) << 16);

    for (int s = 0; s < 4; ++s) {
        const int n0s = blk * 512 + s * 128;
        #pragma unroll
        for (int i = 0; i < 4; ++i) {
            const int f4 = t + i * 256;
            const int ch = f4 >> 5, n4 = (f4 & 31) * 4;
            const long long go = ((long long)ch << 16) + n0s + n4;
            *(float4*)&qs[ch * 132 + n4] = *(const float4*)(qh + go);
            *(float4*)&ks[ch * 132 + n4] = *(const float4*)(kh + go);
        }
        __syncthreads();
        const int nb = w * 32;
        #pragma unroll
        for (int it = 0; it < 8; ++it) {
            const int n = nb + it * 4;
            float4 qa[4], kb[4];
            #pragma unroll
            for (int i = 0; i < 4; ++i) qa[i] = *(const float4*)&qs[(cqd * 4 + i) * 132 + n];
            #pragma unroll
            for (int j = 0; j < 4; ++j) kb[j] = *(const float4*)&ks[(dqd * 4 + j) * 132 + n];
            #pragma unroll
            for (int i = 0; i < 4; ++i) {
                #pragma unroll
                for (int j = 0; j < 4; ++j) {
                    acc[i][j] = fmaf(qa[i].x, kb[j].x, acc[i][j]);
                    acc[i][j] = fmaf(qa[i].y, kb[j].y, acc[i][j]);
                    acc[i][j] = fmaf(qa[i].z, kb[j].z, acc[i][j]);
                    acc[i][j] = fmaf(qa[i].w, kb[j].w, acc[i][j]);
                }
            }
            if (dqd == 0) {
                #pragma unroll
                for (int i = 0; i < 4; ++i) {
                    sq[i] = fmaf(qa[i].x, qa[i].x, sq[i]);
                    sq[i] = fmaf(qa[i].y, qa[i].y, sq[i]);
                    sq[i] = fmaf(qa[i].z, qa[i].z, sq[i]);
                    sq[i] = fmaf(qa[i].w, qa[i].w, sq[i]);
                }
            }
            if (cqd == 0) {
                #pragma unroll
                for (int j = 0; j < 4; ++j) {
                    sk[j] = fmaf(kb[j].x, kb[j].x, sk[j]);
                    sk[j] = fmaf(kb[j].y, kb[j].y, sk[j]);
                    sk[j] = fmaf(kb[j].z, kb[j].z, sk[j]);
                    sk[j] = fmaf(kb[j].w, kb[j].w, sk[j]);
                }
            }
        }
        __syncthreads();
    }

    float* red  = smem;                   // overlays (staging dead post-barrier)
    float* red2 = smem + 4096;
    #pragma unroll
    for (int i = 0; i < 4; ++i) {
        #pragma unroll
        for (int j = 0; j < 4; ++j)
            red[w * 1024 + (cqd * 4 + i) * 32 + dqd * 4 + j] = acc[i][j];
    }
    if (dqd == 0) {
        #pragma unroll
        for (int i = 0; i < 4; ++i) red2[w * 32 + cqd * 4 + i] = sq[i];
    }
    if (cqd == 0) {
        #pragma unroll
        for (int j = 0; j < 4; ++j) red2[128 + w * 32 + dqd * 4 + j] = sk[j];
    }
    __syncthreads();

    float* Gp = Gpart + (long long)(h * 128 + blk) * 1088;
    #pragma unroll
    for (int i = 0; i < 4; ++i) {
        int slot = t + i * 256;
        Gp[slot] = red[slot] + red[1024 + slot] + red[2048 + slot] + red[3072 + slot];
    }
    if (t < 32) {
        Gp[1024 + t] = red2[t] + red2[32 + t] + red2[64 + t] + red2[96 + t];
    } else if (t < 64) {
        int c = t - 32;
        Gp[1056 + c] = red2[128 + c] + red2[160 + c] + red2[192 + c] + red2[224 + c];
    }
}

__global__ void reduce_g(const float* __restrict__ Gpart, float* __restrict__ G,
                         float* __restrict__ Sq, float* __restrict__ Sk, int bh0)
{
    const int h = blockIdx.x, t = threadIdx.x;
    const float* Gp = Gpart + (long long)h * 128 * 1088;
    const int bh = bh0 + h;
    #pragma unroll
    for (int i = 0; i < 5; ++i) {
        int slot = t + i * 256;
        if (slot >= 1088) break;
        float s = 0.f;
        for (int tl = 0; tl < 128; ++tl) s += Gp[(long long)tl * 1088 + slot];
        if (slot < 1024)      G[(long long)bh * 1024 + slot] = s;
        else if (slot < 1056) Sq[bh * 32 + (slot - 1024)] = s;
        else                  Sk[bh * 32 + (slot - 1056)] = s;
    }
}

__global__ void attn_small(const float* __restrict__ G, const float* __restrict__ Sq,
                           const float* __restrict__ Sk, const float* __restrict__ temp,
                           const float* __restrict__ attn1, float* __restrict__ A)
{
    const int h = blockIdx.x, b = blockIdx.y, c = threadIdx.x;
    const int bh = b * 6 + h;
    const float* g = G + ((long long)bh * 32 + c) * 32;
    const float nq = fmaxf(sqrtf(Sq[bh * 32 + c]), 1e-12f);
    const float T  = temp[h];
    const float a1 = attn1[0];

    float a[32];
    #pragma unroll
    for (int d = 0; d < 32; ++d) {
        float nk = fmaxf(sqrtf(Sk[bh * 32 + d]), 1e-12f);
        a[d] = g[d] / (nq * nk) * T;
    }
    unsigned mask = 0u;
    float m = 0.f, kth = 0.f;
    for (int it = 0; it < 16; ++it) {
        float best = -3.4e38f; int bi = 0;
        #pragma unroll
        for (int d = 0; d < 32; ++d) {
            bool avail = ((mask >> d) & 1u) == 0u;
            if (avail && a[d] > best) { best = a[d]; bi = d; }
        }
        mask |= (1u << bi);
        if (it == 0) m = best;
        kth = best;
    }
    float denom = 0.f;
    #pragma unroll
    for (int d = 0; d < 32; ++d) if (a[d] >= kth) denom += expf(a[d] - m);
    const float inv = a1 / denom;
    float* Ar = A + ((long long)bh * 32 + c) * 32;
    #pragma unroll
    for (int d = 0; d < 32; ++d) Ar[d] = (a[d] >= kth) ? expf(a[d] - m) * inv : 0.f;
}

__global__ void make_m(const float* __restrict__ proj_w, const float* __restrict__ A,
                       float* __restrict__ M)
{
    const int o = blockIdx.x, b = blockIdx.y, j = threadIdx.x;
    const int hd = j >> 5, d = j & 31;
    const float* pw = proj_w + o * 192 + hd * 32;
    const float* Ah = A + ((long long)(b * 6 + hd) * 32) * 32 + d;
    float s = 0.f;
    #pragma unroll
    for (int cq = 0; cq < 32; ++cq) s = fmaf(pw[cq], Ah[cq * 32], s);
    M[((long long)(b * 192 + o)) * 192 + j] = s;
}

// ---------------------------------------------------------------------------
extern "C" void kernel_launch(void* const* d_in, const int* in_sizes, int n_in,
                              void* d_out, int out_size, void* d_ws, size_t ws_size,
                              hipStream_t stream)
{
    const float* x      = (const float*)d_in[0];
    const float* qkv_w  = (const float*)d_in[1];
    const float* dww    = (const float*)d_in[2];
    const float* proj_w = (const float*)d_in[3];
    const float* temp   = (const float*)d_in[4];
    const float* attn1  = (const float*)d_in[5];
    float* out = (float*)d_out;
    float* wsf = (float*)d_ws;

    // ws layout (floats) -- proven-safe 101,059,584 bytes total
    float* G   = wsf;                 // 12,288
    float* Sq  = G + 12288;           // 384
    float* Sk  = Sq + 384;            // 384
    float* A   = Sk + 384;            // 12,288
    float* Mm  = A + 12288;           // 73,728
    float* buf = Mm + 73728;          // 96 MiB (= 384 x 65536 floats exactly)

    const long long PL = 12582912LL;  // floats per 48 MiB region
    float* W1 = buf;                  // buf rows 0-191
    float* W2 = buf + PL;             // buf rows 192-383
    float* R1 = out;                  // batch-0 out region (scratch until final)
    float* R2 = out + PL;             // batch-1 out region

    // ---- Phase S (attention statistics) per batch: q,k never persist
    for (int b = 0; b < 2; ++b) {
        const float* xb = x + (long long)b * PL;
        gemm_xf<<<dim3(1536), 256, 0, stream>>>(qkv_w, 0, 6, xb, buf);   // q@W1,k@W2
        dwconv8<<<dim3(32, 48), 256, 0, stream>>>(W1, dww, R1);          // qpost
        dwconv8<<<dim3(32, 48), 256, 0, stream>>>(W2, dww + 192 * 9, R2);// kpost
        gred<<<dim3(128, 6), 256, 0, stream>>>(R1, R2, W1);              // Gpart@W1
        reduce_g<<<dim3(6, 1), 256, 0, stream>>>(W1, G, Sq, Sk, b * 6);
    }

    // ---- Phase B: tiny attention matrices + fused projection matrices
    attn_small<<<dim3(6, 2), 32, 0, stream>>>(G, Sq, Sk, temp, attn1, A);
    make_m<<<dim3(192, 2), 192, 0, stream>>>(proj_w, A, Mm);

    // ---- Phase V+K4 per batch: K1v -> W1 ; dw -> W2 ; out_b = M_b @ vpost
    for (int b = 0; b < 2; ++b) {
        const float* xb = x + (long long)b * PL;
        float* outb = out + (long long)b * PL;
        gemm_xf<<<dim3(768), 256, 0, stream>>>(qkv_w, 384, 3, xb, W1);
        dwconv8<<<dim3(32, 48), 256, 0, stream>>>(W1, dww + 384 * 9, W2);
        gemm_xf<<<dim3(768), 256, 0, stream>>>(Mm + (long long)b * 36864, 0, 3, W2, outb);
    }
}